// Round 15
// baseline (396.034 us; speedup 1.0000x reference)
//
#include <hip/hip_runtime.h>
#include <hip/hip_bf16.h>
#include <cmath>

// Problem constants (B=2, N=1000, k=8 from reference)
#define NB 2
#define NP 1000
#define KNN 8
#define PPAIR 499500  // N*(N-1)/2
#define JSPLIT 8

typedef __hip_bfloat16 bf16;
typedef unsigned long long u64;
typedef unsigned short ushort;
typedef unsigned int uint;
typedef __attribute__((ext_vector_type(8))) short short8;
typedef __attribute__((ext_vector_type(4))) float f32x4;

__device__ __forceinline__ float b2f(bf16 v) { return __bfloat162float(v); }
// f32 -> bf16 bits, round-to-nearest-even
__device__ __forceinline__ ushort f2b(float f) {
    uint x = __float_as_uint(f);
    return (ushort)((x + 0x7FFFu + ((x >> 16) & 1u)) >> 16);
}
// flag-aware element load from an input buffer
__device__ __forceinline__ float ldin(const void* p, int flag, int i) {
    return flag ? ((const float*)p)[i] : b2f(((const bf16*)p)[i]);
}

// Workspace layout (float offsets), all 16B-aligned
#define OFF_POS    0
#define OFF_C1W1   6000
#define OFF_C1B1   6096
#define OFF_C1W2   6112
#define OFF_C1B2   6624
#define OFF_C2W1   6656
#define OFF_C2B1   10752
#define OFF_C2W2   10816
#define OFF_C2B2   19008
#define OFF_C3W1   19136
#define OFF_C3B1   84672
#define OFF_C3W2   84928
#define OFF_C3B2   216000
#define OFF_SMW1   216512
#define OFF_SMB1   388544
#define OFF_SMW2   388800
#define OFF_SMB2   421568
#define OFF_ECW1   421696
#define OFF_ECB1   470848
#define OFF_ECW2   470976
#define OFF_ECB2   471104
#define OFF_X1     471112
#define OFF_X2     535112
#define OFF_X3     791112
#define OFF_SF     1815112
#define OFF_G      2071112
#define OFF_HI     2071368
#define OFF_HJ     2327368
#define OFF_HG     2583368
#define OFF_FLAG   2583624   // int
#define OFF_NIDX   2583632   // 16000 ints
#define OFF_GP     2599632   // 50*128 partial max
#define OFF_W1T    2606032   // ec3 W1T 256x256 bf16 (32768 f32)
#define OFF_W2T    2638800   // ec3 W2T 512x256 bf16 (65536 f32)
#define OFF_SMW1T  2704336   // sm W1T 256x672 bf16 (86016 f32)
#define OFF_SMW2T  2790352   // sm W2T 128x256 bf16 (16384 f32)
#define OFF_ECW1T  2806736   // hij WT 256x128 bf16 (16384 f32)
#define OFF_PL     2823120   // JSPLIT*NB*NP*8 u64 partials (256000 f32)
#define OFF_E2W1T  3079120   // ec2 W1T 64x64 bf16 (2048 f32)
#define OFF_E2W2T  3081168   // ec2 W2T 128x64 bf16 (4096 f32)

// ---------------- dtype detection ----------------
__global__ void detect_kernel(const void* pos, int* flag) {
    __shared__ float red[256];
    const unsigned short* p = (const unsigned short*)pos;
    float m = 0.f;
    for (int t = threadIdx.x; t < 6000; t += 256) {
        unsigned int u = ((unsigned int)p[t]) << 16;
        float v = fabsf(__uint_as_float(u));
        if (!isfinite(v)) v = 1e30f;
        m = fmaxf(m, v);
    }
    red[threadIdx.x] = m;
    __syncthreads();
    for (int s = 128; s > 0; s >>= 1) {
        if (threadIdx.x < s) red[threadIdx.x] = fmaxf(red[threadIdx.x], red[threadIdx.x + s]);
        __syncthreads();
    }
    if (threadIdx.x == 0) flag[0] = (red[0] > 1e6f) ? 1 : 0;
}

// ---------------- convert inputs to f32 + build transposed bf16 weights ----------------
struct InPtrs { const void* p[21]; };

__global__ void cvt_all_kernel(InPtrs in, float* ws, const int* flag,
                               ushort* w1t, ushort* w2t, ushort* smw1t,
                               ushort* smw2t, ushort* ecw1t,
                               ushort* e2w1t, ushort* e2w2t) {
    const int sizes[21] = {6000, 96, 16, 512, 32, 4096, 64, 8192, 128,
                           65536, 256, 131072, 512, 172032, 256, 32768, 128,
                           49152, 128, 128, 1};
    const int offs[21] = {OFF_POS, OFF_C1W1, OFF_C1B1, OFF_C1W2, OFF_C1B2,
                          OFF_C2W1, OFF_C2B1, OFF_C2W2, OFF_C2B2,
                          OFF_C3W1, OFF_C3B1, OFF_C3W2, OFF_C3B2,
                          OFF_SMW1, OFF_SMB1, OFF_SMW2, OFF_SMB2,
                          OFF_ECW1, OFF_ECB1, OFF_ECW2, OFF_ECB2};
    int y = blockIdx.y;
    int t = blockIdx.x * 256 + threadIdx.x;
    int f = flag[0];
    if (y < 21) {
        if (t < sizes[y]) ws[offs[y] + t] = ldin(in.p[y], f, t);
    } else if (y == 21) {
        if (t < 65536) {            // ec3 W1 [c=256][h=256] -> [h][c]
            int h = t >> 8, c = t & 255;
            w1t[t] = f2b(ldin(in.p[9], f, c * 256 + h));
        }
    } else if (y == 22) {
        if (t < 131072) {           // ec3 W2 [h=256][o=512] -> [o][h]
            int o = t >> 8, h = t & 255;
            w2t[t] = f2b(ldin(in.p[11], f, h * 512 + o));
        }
    } else if (y == 23) {
        if (t < 172032) {           // sm W1 [c=672][h=256] -> [h][c]
            int h = t / 672, c = t - h * 672;
            smw1t[t] = f2b(ldin(in.p[13], f, c * 256 + h));
        }
    } else if (y == 24) {
        if (t < 32768) {            // sm W2 [h=256][o=128] -> [o][h]
            int o = t >> 8, h = t & 255;
            smw2t[t] = f2b(ldin(in.p[15], f, h * 128 + o));
        }
    } else if (y == 25) {
        if (t < 32768) {            // ec W1[:256] -> [o'][c]
            int op = t >> 7, c = t & 127;
            int idx = (op < 128) ? (c * 128 + op) : ((128 + c) * 128 + (op - 128));
            ecw1t[t] = f2b(ldin(in.p[17], f, idx));
        }
    } else if (y == 26) {
        if (t < 4096) {             // ec2 W1 [c=64][h=64] -> [h][c]
            int h = t >> 6, c = t & 63;
            e2w1t[t] = f2b(ldin(in.p[5], f, c * 64 + h));
        }
    } else {
        if (t < 8192) {             // ec2 W2 [h=64][o=128] -> [o][h]
            int o = t >> 6, h = t & 63;
            e2w2t[t] = f2b(ldin(in.p[7], f, h * 128 + o));
        }
    }
}

// ---------------- shared kNN helpers ----------------
__device__ __forceinline__ void ce(u64& a, u64& b) {
    u64 lo = a < b ? a : b;
    u64 hi = a < b ? b : a;
    a = lo; b = hi;
}

__device__ __forceinline__ void ins8(u64 (&best)[KNN], u64 cand) {
    u64 cur = cand;
    #pragma unroll
    for (int r = 0; r < KNN; ++r) {
        u64 lo = best[r] < cur ? best[r] : cur;
        u64 hi = best[r] < cur ? cur : best[r];
        best[r] = lo; cur = hi;
    }
}

// ---------------- kNN v5: register-tiled dist + partial top-8 (E2E-verified @C=128) ----------------
// For C%4!=0 (C=3): scalar-guarded row loads, pad = 0 on both sides (0 contribution).
template <int C>
__global__ __launch_bounds__(256) void knn5_kernel(const float* __restrict__ x,
                                                   u64* __restrict__ pl) {
    constexpr int CP = (C + 3) & ~3;
    constexpr int STR = CP + 4;
    __shared__ float As[32 * STR];
    __shared__ float Bs[64 * STR];
    int tid = threadIdx.x;
    int tx = tid & 31, ty = tid >> 5;
    int b = blockIdx.z;
    int i0 = blockIdx.x * 32;
    int jbase = blockIdx.y * 128;

    for (int idx = tid; idx < 32 * (CP / 4); idx += 256) {
        int row = idx / (CP / 4), c4 = idx % (CP / 4);
        int i = i0 + row;
        float4 v = make_float4(0.f, 0.f, 0.f, 0.f);
        if (i < NP) {
            if (C % 4 == 0) v = *(const float4*)(x + ((size_t)b * NP + i) * C + c4 * 4);
            else {
                const float* xp = x + ((size_t)b * NP + i) * C;
                v = make_float4(xp[0], xp[1], xp[2], 0.f);
            }
        }
        *(float4*)(&As[row * STR + c4 * 4]) = v;
    }

    u64 best[4][KNN];
    #pragma unroll
    for (int r = 0; r < 4; ++r)
        #pragma unroll
        for (int s = 0; s < KNN; ++s) best[r][s] = ~0ull;

    for (int jc = 0; jc < 2; ++jc) {
        int j0 = jbase + jc * 64;
        __syncthreads();
        for (int idx = tid; idx < 64 * (CP / 4); idx += 256) {
            int row = idx / (CP / 4), c4 = idx % (CP / 4);
            int j = j0 + row;
            float4 v = make_float4(0.f, 0.f, 0.f, 0.f);
            if (j < NP) {
                if (C % 4 == 0) v = *(const float4*)(x + ((size_t)b * NP + j) * C + c4 * 4);
                else {
                    const float* xp = x + ((size_t)b * NP + j) * C;
                    v = make_float4(xp[0], xp[1], xp[2], 0.f);
                }
            }
            *(float4*)(&Bs[row * STR + c4 * 4]) = v;
        }
        __syncthreads();

        float acc[4][2];
        #pragma unroll
        for (int r = 0; r < 4; ++r) { acc[r][0] = 0.f; acc[r][1] = 0.f; }
        #pragma unroll 4
        for (int k4 = 0; k4 < CP / 4; ++k4) {
            float4 b0 = *(const float4*)(&Bs[tx * STR + k4 * 4]);
            float4 b1 = *(const float4*)(&Bs[(tx + 32) * STR + k4 * 4]);
            #pragma unroll
            for (int r = 0; r < 4; ++r) {
                float4 a = *(const float4*)(&As[(ty * 4 + r) * STR + k4 * 4]);
                float d;
                d = a.x - b0.x; acc[r][0] += d * d;  d = a.x - b1.x; acc[r][1] += d * d;
                d = a.y - b0.y; acc[r][0] += d * d;  d = a.y - b1.y; acc[r][1] += d * d;
                d = a.z - b0.z; acc[r][0] += d * d;  d = a.z - b1.z; acc[r][1] += d * d;
                d = a.w - b0.w; acc[r][0] += d * d;  d = a.w - b1.w; acc[r][1] += d * d;
            }
        }
        int ja = j0 + tx, jb = j0 + tx + 32;
        #pragma unroll
        for (int r = 0; r < 4; ++r) {
            u64 ca = (ja < NP) ? ((((u64)__float_as_uint(acc[r][0])) << 32) | (unsigned)ja) : ~0ull;
            u64 cb = (jb < NP) ? ((((u64)__float_as_uint(acc[r][1])) << 32) | (unsigned)jb) : ~0ull;
            ins8(best[r], ca);
            ins8(best[r], cb);
        }
    }

    #pragma unroll
    for (int m = 1; m < 32; m <<= 1) {
        #pragma unroll
        for (int r = 0; r < 4; ++r) {
            u64 other[KNN];
            #pragma unroll
            for (int s = 0; s < KNN; ++s)
                other[s] = __shfl_xor((unsigned long long)best[r][s], m, 64);
            u64 v[KNN];
            #pragma unroll
            for (int s = 0; s < KNN; ++s)
                v[s] = best[r][s] < other[7 - s] ? best[r][s] : other[7 - s];
            ce(v[0], v[4]); ce(v[1], v[5]); ce(v[2], v[6]); ce(v[3], v[7]);
            ce(v[0], v[2]); ce(v[1], v[3]); ce(v[4], v[6]); ce(v[5], v[7]);
            ce(v[0], v[1]); ce(v[2], v[3]); ce(v[4], v[5]); ce(v[6], v[7]);
            #pragma unroll
            for (int s = 0; s < KNN; ++s) best[r][s] = v[s];
        }
    }

    if (tx == 0) {
        #pragma unroll
        for (int r = 0; r < 4; ++r) {
            int i = i0 + ty * 4 + r;
            if (i < NP) {
                size_t base = ((size_t)blockIdx.y * NB * NP + (size_t)b * NP + i) * KNN;
                #pragma unroll
                for (int s = 0; s < KNN; ++s) pl[base + s] = best[r][s];
            }
        }
    }
}

// merge JSPLIT partial lists per query -> final top-8 indices
__global__ void knn_merge_kernel(const u64* __restrict__ pl, int* __restrict__ nidx) {
    int t = blockIdx.x * 256 + threadIdx.x;
    if (t >= NB * NP) return;
    u64 best[KNN];
    #pragma unroll
    for (int s = 0; s < KNN; ++s) best[s] = ~0ull;
    for (int js = 0; js < JSPLIT; ++js) {
        #pragma unroll
        for (int s = 0; s < KNN; ++s)
            ins8(best, pl[((size_t)js * NB * NP + t) * KNN + s]);
    }
    #pragma unroll
    for (int s = 0; s < KNN; ++s)
        nidx[(size_t)t * KNN + s] = (int)(best[s] & 0xffffffffu);
}

// ---------------- fused EdgeConv (f32, layer 1 only) ----------------
template <int CIN, int CHID, int COUT>
__global__ void edgeconv_kernel(const float* __restrict__ x, const int* __restrict__ nidx,
                                const float* __restrict__ w1, const float* __restrict__ b1,
                                const float* __restrict__ w2, const float* __restrict__ b2,
                                float* __restrict__ y) {
    int bi = blockIdx.x;
    int b = bi / NP;
    __shared__ float xi[CIN];
    __shared__ float dx[KNN][CIN];
    __shared__ __align__(16) float hid[CHID][12];
    __shared__ int nb[KNN];
    int tid = threadIdx.x;
    if (tid < KNN) nb[tid] = nidx[bi * KNN + tid];
    for (int c = tid; c < CIN; c += 256) xi[c] = x[(size_t)bi * CIN + c];
    __syncthreads();
    for (int t = tid; t < KNN * CIN; t += 256) {
        int k = t / CIN, c = t % CIN;
        dx[k][c] = x[((size_t)b * NP + nb[k]) * CIN + c] - xi[c];
    }
    __syncthreads();
    for (int h = tid; h < CHID; h += 256) {
        float common = b1[h];
        for (int c = 0; c < CIN; ++c) common += xi[c] * w1[c * CHID + h];
        float acc[KNN];
        for (int k = 0; k < KNN; ++k) acc[k] = common;
        for (int c = 0; c < CIN; ++c) {
            float wv = w1[(CIN + c) * CHID + h];
            for (int k = 0; k < KNN; ++k) acc[k] += dx[k][c] * wv;
        }
        for (int k = 0; k < KNN; ++k) hid[h][k] = fmaxf(acc[k], 0.f);
    }
    __syncthreads();
    for (int o = tid; o < COUT; o += 256) {
        float acc[KNN];
        for (int k = 0; k < KNN; ++k) acc[k] = 0.f;
        for (int h = 0; h < CHID; ++h) {
            float wv = w2[h * COUT + o];
            float4 h0 = *(const float4*)&hid[h][0];
            float4 h1 = *(const float4*)&hid[h][4];
            acc[0] += h0.x * wv; acc[1] += h0.y * wv; acc[2] += h0.z * wv; acc[3] += h0.w * wv;
            acc[4] += h1.x * wv; acc[5] += h1.y * wv; acc[6] += h1.z * wv; acc[7] += h1.w * wv;
        }
        float m = acc[0];
        for (int k = 1; k < KNN; ++k) m = fmaxf(m, acc[k]);
        y[(size_t)bi * COUT + o] = m + b2[o];
    }
}

// ---------------- EdgeConv-2 via bf16 MFMA (ec3 template, K=64) ----------------
#define E2STR 72
__global__ __launch_bounds__(256) void ec2_mfma_kernel(
        const float* __restrict__ x1, const int* __restrict__ nidx,
        const ushort* __restrict__ w1t, const ushort* __restrict__ w2t,
        const float* __restrict__ b1f, const float* __restrict__ b2f,
        float* __restrict__ x2out) {
    __shared__ ushort Elds[32 * E2STR];
    __shared__ ushort Hlds[32 * E2STR];
    int tid = threadIdx.x;
    int P0 = blockIdx.x * 4;

    {
        int e = tid >> 3, seg = tid & 7;
        int bi = P0 + (e >> 3), k = e & 7;
        int b = bi / NP;
        int nb = nidx[bi * KNN + k];
        const float* xi = x1 + (size_t)bi * 32;
        const float* xj = x1 + ((size_t)b * NP + nb) * 32;
        int c0 = seg * 8;
        #pragma unroll
        for (int c = c0; c < c0 + 8; c += 4) {
            float4 v;
            if (c < 32) {
                v = *(const float4*)(xi + c);
            } else {
                float4 a = *(const float4*)(xi + c - 32);
                float4 q = *(const float4*)(xj + c - 32);
                v = make_float4(q.x - a.x, q.y - a.y, q.z - a.z, q.w - a.w);
            }
            uint lo = (uint)f2b(v.x) | ((uint)f2b(v.y) << 16);
            uint hi = (uint)f2b(v.z) | ((uint)f2b(v.w) << 16);
            *(uint2*)(&Elds[e * E2STR + c]) = make_uint2(lo, hi);
        }
    }
    __syncthreads();

    int lane = tid & 63, wave = tid >> 6;
    int n16 = lane & 15, quad = lane >> 4;

    {
        int nc = wave * 16;
        f32x4 acc[2];
        float bv = b1f[nc + n16];
        acc[0] = (f32x4){bv, bv, bv, bv};
        acc[1] = acc[0];
        #pragma unroll
        for (int k8 = 0; k8 < 2; ++k8) {
            int ko = k8 * 32 + quad * 8;
            short8 a0 = *(const short8*)(&Elds[(n16) * E2STR + ko]);
            short8 a1 = *(const short8*)(&Elds[(16 + n16) * E2STR + ko]);
            short8 bfr = *(const short8*)(&w1t[(size_t)(nc + n16) * 64 + ko]);
            acc[0] = __builtin_amdgcn_mfma_f32_16x16x32_bf16(a0, bfr, acc[0], 0, 0, 0);
            acc[1] = __builtin_amdgcn_mfma_f32_16x16x32_bf16(a1, bfr, acc[1], 0, 0, 0);
        }
        #pragma unroll
        for (int mt = 0; mt < 2; ++mt) {
            int col = nc + n16;
            #pragma unroll
            for (int r = 0; r < 4; ++r) {
                int row = mt * 16 + quad * 4 + r;
                Hlds[row * E2STR + col] = f2b(fmaxf(acc[mt][r], 0.f));
            }
        }
    }
    __syncthreads();

    {
        int nc2 = wave * 32;
        f32x4 acc[2][2];
        #pragma unroll
        for (int mt = 0; mt < 2; ++mt)
            #pragma unroll
            for (int nt = 0; nt < 2; ++nt) acc[mt][nt] = (f32x4){0.f, 0.f, 0.f, 0.f};
        #pragma unroll
        for (int k8 = 0; k8 < 2; ++k8) {
            int ko = k8 * 32 + quad * 8;
            short8 a0 = *(const short8*)(&Hlds[(n16) * E2STR + ko]);
            short8 a1 = *(const short8*)(&Hlds[(16 + n16) * E2STR + ko]);
            #pragma unroll
            for (int nt = 0; nt < 2; ++nt) {
                short8 bfr = *(const short8*)(&w2t[(size_t)(nc2 + nt * 16 + n16) * 64 + ko]);
                acc[0][nt] = __builtin_amdgcn_mfma_f32_16x16x32_bf16(a0, bfr, acc[0][nt], 0, 0, 0);
                acc[1][nt] = __builtin_amdgcn_mfma_f32_16x16x32_bf16(a1, bfr, acc[1][nt], 0, 0, 0);
            }
        }
        #pragma unroll
        for (int mt = 0; mt < 2; ++mt)
            #pragma unroll
            for (int nt = 0; nt < 2; ++nt) {
                f32x4 a = acc[mt][nt];
                float v = fmaxf(fmaxf(a[0], a[1]), fmaxf(a[2], a[3]));
                float o = fmaxf(v, __shfl_xor(v, 16, 64));
                int col = nc2 + nt * 16 + n16;
                if (quad == 0)
                    x2out[(size_t)(P0 + mt * 2) * 128 + col] = o + b2f[col];
                else if (quad == 2)
                    x2out[(size_t)(P0 + mt * 2 + 1) * 128 + col] = o + b2f[col];
            }
    }
}

// ---------------- EdgeConv-3 via bf16 MFMA, fully fused ----------------
#define ESTR 264   // LDS row stride (bf16 elems)
__global__ __launch_bounds__(256) void ec3_mfma_kernel(
        const float* __restrict__ x2, const int* __restrict__ nidx,
        const ushort* __restrict__ w1t, const ushort* __restrict__ w2t,
        const float* __restrict__ b1f, const float* __restrict__ b2f,
        float* __restrict__ x3) {
    __shared__ ushort Elds[32 * ESTR];
    __shared__ ushort Hlds[32 * ESTR];
    int tid = threadIdx.x;
    int P0 = blockIdx.x * 4;

    {
        int e = tid >> 3, seg = tid & 7;
        int bi = P0 + (e >> 3), k = e & 7;
        int b = bi / NP;
        int nb = nidx[bi * KNN + k];
        const float* xi = x2 + (size_t)bi * 128;
        const float* xj = x2 + ((size_t)b * NP + nb) * 128;
        int c0 = seg * 16;
        #pragma unroll
        for (int c = c0; c < c0 + 16; c += 4) {
            float4 a = *(const float4*)(xi + c);
            float4 q = *(const float4*)(xj + c);
            uint lo = (uint)f2b(a.x) | ((uint)f2b(a.y) << 16);
            uint hi = (uint)f2b(a.z) | ((uint)f2b(a.w) << 16);
            *(uint2*)(&Elds[e * ESTR + c]) = make_uint2(lo, hi);
            lo = (uint)f2b(q.x - a.x) | ((uint)f2b(q.y - a.y) << 16);
            hi = (uint)f2b(q.z - a.z) | ((uint)f2b(q.w - a.w) << 16);
            *(uint2*)(&Elds[e * ESTR + 128 + c]) = make_uint2(lo, hi);
        }
    }
    __syncthreads();

    int lane = tid & 63, wave = tid >> 6;
    int n16 = lane & 15, quad = lane >> 4;

    {
        int nc = wave * 64;
        f32x4 acc1[2][4];
        #pragma unroll
        for (int mt = 0; mt < 2; ++mt)
            #pragma unroll
            for (int nt = 0; nt < 4; ++nt) {
                float bv = b1f[nc + nt * 16 + n16];
                acc1[mt][nt] = (f32x4){bv, bv, bv, bv};
            }
        #pragma unroll
        for (int k8 = 0; k8 < 8; ++k8) {
            int ko = k8 * 32 + quad * 8;
            short8 a0 = *(const short8*)(&Elds[(n16) * ESTR + ko]);
            short8 a1 = *(const short8*)(&Elds[(16 + n16) * ESTR + ko]);
            #pragma unroll
            for (int nt = 0; nt < 4; ++nt) {
                short8 bfr = *(const short8*)(&w1t[(size_t)(nc + nt * 16 + n16) * 256 + ko]);
                acc1[0][nt] = __builtin_amdgcn_mfma_f32_16x16x32_bf16(a0, bfr, acc1[0][nt], 0, 0, 0);
                acc1[1][nt] = __builtin_amdgcn_mfma_f32_16x16x32_bf16(a1, bfr, acc1[1][nt], 0, 0, 0);
            }
        }
        #pragma unroll
        for (int mt = 0; mt < 2; ++mt)
            #pragma unroll
            for (int nt = 0; nt < 4; ++nt) {
                int col = nc + nt * 16 + n16;
                #pragma unroll
                for (int r = 0; r < 4; ++r) {
                    int row = mt * 16 + quad * 4 + r;
                    Hlds[row * ESTR + col] = f2b(fmaxf(acc1[mt][nt][r], 0.f));
                }
            }
    }
    __syncthreads();

    {
        int nc2 = wave * 128;
        f32x4 acc2[2][8];
        #pragma unroll
        for (int mt = 0; mt < 2; ++mt)
            #pragma unroll
            for (int nt = 0; nt < 8; ++nt) acc2[mt][nt] = (f32x4){0.f, 0.f, 0.f, 0.f};
        #pragma unroll
        for (int k8 = 0; k8 < 8; ++k8) {
            int ko = k8 * 32 + quad * 8;
            short8 a0 = *(const short8*)(&Hlds[(n16) * ESTR + ko]);
            short8 a1 = *(const short8*)(&Hlds[(16 + n16) * ESTR + ko]);
            #pragma unroll
            for (int nt = 0; nt < 8; ++nt) {
                short8 bfr = *(const short8*)(&w2t[(size_t)(nc2 + nt * 16 + n16) * 256 + ko]);
                acc2[0][nt] = __builtin_amdgcn_mfma_f32_16x16x32_bf16(a0, bfr, acc2[0][nt], 0, 0, 0);
                acc2[1][nt] = __builtin_amdgcn_mfma_f32_16x16x32_bf16(a1, bfr, acc2[1][nt], 0, 0, 0);
            }
        }
        #pragma unroll
        for (int mt = 0; mt < 2; ++mt)
            #pragma unroll
            for (int nt = 0; nt < 8; ++nt) {
                f32x4 a = acc2[mt][nt];
                float v = fmaxf(fmaxf(a[0], a[1]), fmaxf(a[2], a[3]));
                float o = fmaxf(v, __shfl_xor(v, 16, 64));
                int col = nc2 + nt * 16 + n16;
                if (quad == 0)
                    x3[(size_t)(P0 + mt * 2) * 512 + col] = o + b2f[col];
                else if (quad == 2)
                    x3[(size_t)(P0 + mt * 2 + 1) * 512 + col] = o + b2f[col];
            }
    }
}

// ---------------- shared MLP + hij via bf16 MFMA, fully fused ----------------
#define XSTR 680   // 672+8 bf16
#define SSTR 136   // 128+8
__global__ __launch_bounds__(256) void sm_mfma_kernel(
        const float* __restrict__ x1, const float* __restrict__ x2,
        const float* __restrict__ x3,
        const ushort* __restrict__ w1t, const ushort* __restrict__ w2t,
        const ushort* __restrict__ ecw1t,
        const float* __restrict__ b1f, const float* __restrict__ b2f,
        float* __restrict__ sf, float* __restrict__ hi, float* __restrict__ hj) {
    __shared__ ushort Xlds[32 * XSTR];
    __shared__ ushort Hlds[32 * ESTR];
    __shared__ ushort Slds[32 * SSTR];
    int tid = threadIdx.x;
    int P0 = blockIdx.x * 32;

    {
        int row = tid >> 3, cseg = tid & 7;
        int p = P0 + row;
        bool ok = p < NB * NP;
        #pragma unroll
        for (int k = 0; k < 21; ++k) {
            int c = cseg * 4 + k * 32;
            float4 v = make_float4(0.f, 0.f, 0.f, 0.f);
            if (ok) {
                if (c < 32) v = *(const float4*)(x1 + (size_t)p * 32 + c);
                else if (c < 160) v = *(const float4*)(x2 + (size_t)p * 128 + (c - 32));
                else v = *(const float4*)(x3 + (size_t)p * 512 + (c - 160));
            }
            uint lo = (uint)f2b(v.x) | ((uint)f2b(v.y) << 16);
            uint hv = (uint)f2b(v.z) | ((uint)f2b(v.w) << 16);
            *(uint2*)(&Xlds[row * XSTR + c]) = make_uint2(lo, hv);
        }
    }
    __syncthreads();

    int lane = tid & 63, wave = tid >> 6;
    int n16 = lane & 15, quad = lane >> 4;

    {
        int nc = wave * 64;
        f32x4 acc[2][4];
        #pragma unroll
        for (int mt = 0; mt < 2; ++mt)
            #pragma unroll
            for (int nt = 0; nt < 4; ++nt) {
                float bv = b1f[nc + nt * 16 + n16];
                acc[mt][nt] = (f32x4){bv, bv, bv, bv};
            }
        #pragma unroll
        for (int k8 = 0; k8 < 21; ++k8) {
            int ko = k8 * 32 + quad * 8;
            short8 a0 = *(const short8*)(&Xlds[(n16) * XSTR + ko]);
            short8 a1 = *(const short8*)(&Xlds[(16 + n16) * XSTR + ko]);
            #pragma unroll
            for (int nt = 0; nt < 4; ++nt) {
                short8 bfr = *(const short8*)(&w1t[(size_t)(nc + nt * 16 + n16) * 672 + ko]);
                acc[0][nt] = __builtin_amdgcn_mfma_f32_16x16x32_bf16(a0, bfr, acc[0][nt], 0, 0, 0);
                acc[1][nt] = __builtin_amdgcn_mfma_f32_16x16x32_bf16(a1, bfr, acc[1][nt], 0, 0, 0);
            }
        }
        #pragma unroll
        for (int mt = 0; mt < 2; ++mt)
            #pragma unroll
            for (int nt = 0; nt < 4; ++nt) {
                int col = nc + nt * 16 + n16;
                #pragma unroll
                for (int r = 0; r < 4; ++r) {
                    int row = mt * 16 + quad * 4 + r;
                    Hlds[row * ESTR + col] = f2b(fmaxf(acc[mt][nt][r], 0.f));
                }
            }
    }
    __syncthreads();

    {
        int nc = wave * 32;
        f32x4 acc[2][2];
        #pragma unroll
        for (int mt = 0; mt < 2; ++mt)
            #pragma unroll
            for (int nt = 0; nt < 2; ++nt) {
                float bv = b2f[nc + nt * 16 + n16];
                acc[mt][nt] = (f32x4){bv, bv, bv, bv};
            }
        #pragma unroll
        for (int k8 = 0; k8 < 8; ++k8) {
            int ko = k8 * 32 + quad * 8;
            short8 a0 = *(const short8*)(&Hlds[(n16) * ESTR + ko]);
            short8 a1 = *(const short8*)(&Hlds[(16 + n16) * ESTR + ko]);
            #pragma unroll
            for (int nt = 0; nt < 2; ++nt) {
                short8 bfr = *(const short8*)(&w2t[(size_t)(nc + nt * 16 + n16) * 256 + ko]);
                acc[0][nt] = __builtin_amdgcn_mfma_f32_16x16x32_bf16(a0, bfr, acc[0][nt], 0, 0, 0);
                acc[1][nt] = __builtin_amdgcn_mfma_f32_16x16x32_bf16(a1, bfr, acc[1][nt], 0, 0, 0);
            }
        }
        #pragma unroll
        for (int mt = 0; mt < 2; ++mt)
            #pragma unroll
            for (int nt = 0; nt < 2; ++nt) {
                int col = nc + nt * 16 + n16;
                #pragma unroll
                for (int r = 0; r < 4; ++r) {
                    int row = mt * 16 + quad * 4 + r;
                    int p = P0 + row;
                    float v = acc[mt][nt][r];
                    if (p < NB * NP) sf[(size_t)p * 128 + col] = v;
                    Slds[row * SSTR + col] = f2b(v);
                }
            }
    }
    __syncthreads();

    {
        int nc = wave * 64;
        f32x4 acc[2][4];
        #pragma unroll
        for (int mt = 0; mt < 2; ++mt)
            #pragma unroll
            for (int nt = 0; nt < 4; ++nt) acc[mt][nt] = (f32x4){0.f, 0.f, 0.f, 0.f};
        #pragma unroll
        for (int k8 = 0; k8 < 4; ++k8) {
            int ko = k8 * 32 + quad * 8;
            short8 a0 = *(const short8*)(&Slds[(n16) * SSTR + ko]);
            short8 a1 = *(const short8*)(&Slds[(16 + n16) * SSTR + ko]);
            #pragma unroll
            for (int nt = 0; nt < 4; ++nt) {
                short8 bfr = *(const short8*)(&ecw1t[(size_t)(nc + nt * 16 + n16) * 128 + ko]);
                acc[0][nt] = __builtin_amdgcn_mfma_f32_16x16x32_bf16(a0, bfr, acc[0][nt], 0, 0, 0);
                acc[1][nt] = __builtin_amdgcn_mfma_f32_16x16x32_bf16(a1, bfr, acc[1][nt], 0, 0, 0);
            }
        }
        #pragma unroll
        for (int mt = 0; mt < 2; ++mt)
            #pragma unroll
            for (int nt = 0; nt < 4; ++nt) {
                int colp = nc + nt * 16 + n16;
                float* dst = (colp < 128) ? hi : hj;
                int col = colp & 127;
                #pragma unroll
                for (int r = 0; r < 4; ++r) {
                    int row = mt * 16 + quad * 4 + r;
                    int p = P0 + row;
                    if (p < NB * NP) dst[(size_t)p * 128 + col] = acc[mt][nt][r];
                }
            }
    }
}

// ---------------- global max pool stage 1 ----------------
__global__ void gmax1_kernel(const float* __restrict__ sf, float* __restrict__ part) {
    int m = blockIdx.x;
    int b = m / 25, ch = m % 25, o = threadIdx.x;
    float v = -INFINITY;
    int n0 = ch * 40;
    for (int n = n0; n < n0 + 40; ++n)
        v = fmaxf(v, sf[((size_t)b * NP + n) * 128 + o]);
    part[(size_t)m * 128 + o] = v;
}

// ---------------- fused final max + hg = g @ W[256:384] + b1 ----------------
__global__ void gfin_kernel(const float* __restrict__ part, const float* __restrict__ w1,
                            const float* __restrict__ b1, float* __restrict__ hg) {
    int b = blockIdx.x, o = threadIdx.x;   // 128 threads
    __shared__ float gs[128];
    float v = -INFINITY;
    for (int ch = 0; ch < 25; ++ch)
        v = fmaxf(v, part[((size_t)b * 25 + ch) * 128 + o]);
    gs[o] = v;
    __syncthreads();
    float acc = b1[o];
    for (int c = 0; c < 128; ++c) acc += gs[c] * w1[(256 + c) * 128 + o];
    hg[b * 128 + o] = acc;
}

// ---------------- pairwise scorer: 32x32 tiles, float4 o-loop (R14-proven) ----------------
__global__ __launch_bounds__(256) void pair_kernel(
        const float* __restrict__ hi, const float* __restrict__ hj,
        const float* __restrict__ hg,
        const float* __restrict__ w2, const float* __restrict__ b2,
        void* __restrict__ out, const int* __restrict__ flag) {
    int j0 = blockIdx.x * 32, i0 = blockIdx.y * 32, b = blockIdx.z;
    if (j0 + 31 <= i0) return;
    __shared__ float hit[32][132];
    __shared__ float hjt[32][132];
    __shared__ __align__(16) float w2s[128];
    int tid = threadIdx.x;
    if (tid < 128) w2s[tid] = w2[tid];
    for (int t = tid; t < 32 * 128; t += 256) {
        int r = t >> 7, c = t & 127;
        int i = i0 + r, j = j0 + r;
        hit[r][c] = (i < NP) ? hi[((size_t)b * NP + i) * 128 + c] : 0.f;
        hjt[r][c] = ((j < NP) ? hj[((size_t)b * NP + j) * 128 + c] : 0.f) + hg[b * 128 + c];
    }
    __syncthreads();
    float bb = b2[0];
    int f = flag[0];
    int tj = tid & 31;
    int ti0 = tid >> 5;
    int j = j0 + tj;
    float acc[4] = {0.f, 0.f, 0.f, 0.f};
    #pragma unroll 4
    for (int o4 = 0; o4 < 32; ++o4) {
        float4 hv = *(const float4*)(&hjt[tj][o4 * 4]);
        float4 wv = *(const float4*)(&w2s[o4 * 4]);
        #pragma unroll
        for (int r = 0; r < 4; ++r) {
            float4 a = *(const float4*)(&hit[ti0 + 8 * r][o4 * 4]);
            acc[r] += fmaxf(a.x + hv.x, 0.f) * wv.x
                    + fmaxf(a.y + hv.y, 0.f) * wv.y
                    + fmaxf(a.z + hv.z, 0.f) * wv.z
                    + fmaxf(a.w + hv.w, 0.f) * wv.w;
        }
    }
    #pragma unroll
    for (int r = 0; r < 4; ++r) {
        int i = i0 + ti0 + 8 * r;
        if (i < j && j < NP) {
            size_t p = (size_t)i * (NP - 1) - (size_t)i * (i - 1) / 2 + (j - i - 1);
            float mo = acc[r] + bb;
            float pr = 1.f / (1.f + expf(-mo));
            size_t idx0 = (size_t)b * PPAIR + p;
            size_t idx1 = (size_t)NB * PPAIR + idx0;
            if (f) {
                ((float*)out)[idx0] = pr;
                ((float*)out)[idx1] = mo;
            } else {
                ((bf16*)out)[idx0] = __float2bfloat16(pr);
                ((bf16*)out)[idx1] = __float2bfloat16(mo);
            }
        }
    }
}

extern "C" void kernel_launch(void* const* d_in, const int* in_sizes, int n_in,
                              void* d_out, int out_size, void* d_ws, size_t ws_size,
                              hipStream_t stream) {
    float* ws = (float*)d_ws;
    float* posf = ws + OFF_POS;
    float* x1   = ws + OFF_X1;
    float* x2   = ws + OFF_X2;
    float* x3   = ws + OFF_X3;
    float* sf   = ws + OFF_SF;
    float* hi   = ws + OFF_HI;
    float* hj   = ws + OFF_HJ;
    float* hgb  = ws + OFF_HG;
    int*   flag = (int*)(ws + OFF_FLAG);
    int*   nidx = (int*)(ws + OFF_NIDX);
    float* gp   = ws + OFF_GP;
    ushort* w1t = (ushort*)(ws + OFF_W1T);
    ushort* w2t = (ushort*)(ws + OFF_W2T);
    ushort* smw1t = (ushort*)(ws + OFF_SMW1T);
    ushort* smw2t = (ushort*)(ws + OFF_SMW2T);
    ushort* ecw1t = (ushort*)(ws + OFF_ECW1T);
    ushort* e2w1t = (ushort*)(ws + OFF_E2W1T);
    ushort* e2w2t = (ushort*)(ws + OFF_E2W2T);
    u64*    pl  = (u64*)(ws + OFF_PL);

    // 1) detect input dtype (bf16 vs f32) on-device
    detect_kernel<<<1, 256, 0, stream>>>(d_in[0], flag);

    // 2) convert all inputs to f32 + build all transposed bf16 weights (one kernel)
    InPtrs ip;
    for (int i = 0; i < 21; ++i) ip.p[i] = d_in[i];
    dim3 cgrid(672, 28);
    cvt_all_kernel<<<cgrid, 256, 0, stream>>>(ip, ws, flag, w1t, w2t, smw1t, smw2t,
                                              ecw1t, e2w1t, e2w2t);

    dim3 kgrid5((NP + 31) / 32, JSPLIT, NB);       // knn5 grid (all layers)
    int mgrid = (NB * NP + 255) / 256;

    // 3) EdgeConv 1 (C=3 -> 32)
    knn5_kernel<3><<<kgrid5, 256, 0, stream>>>(posf, pl);
    knn_merge_kernel<<<mgrid, 256, 0, stream>>>(pl, nidx);
    edgeconv_kernel<3, 16, 32><<<NB * NP, 256, 0, stream>>>(
        posf, nidx, ws + OFF_C1W1, ws + OFF_C1B1, ws + OFF_C1W2, ws + OFF_C1B2, x1);

    // 4) EdgeConv 2 (C=32 -> 128) via MFMA
    knn5_kernel<32><<<kgrid5, 256, 0, stream>>>(x1, pl);
    knn_merge_kernel<<<mgrid, 256, 0, stream>>>(pl, nidx);
    ec2_mfma_kernel<<<NB * NP / 4, 256, 0, stream>>>(
        x1, nidx, e2w1t, e2w2t, ws + OFF_C2B1, ws + OFF_C2B2, x2);

    // 5) EdgeConv 3 (C=128 -> 512) via MFMA
    knn5_kernel<128><<<kgrid5, 256, 0, stream>>>(x2, pl);
    knn_merge_kernel<<<mgrid, 256, 0, stream>>>(pl, nidx);
    ec3_mfma_kernel<<<NB * NP / 4, 256, 0, stream>>>(
        x2, nidx, w1t, w2t, ws + OFF_C3B1, ws + OFF_C3B2, x3);

    // 6) shared MLP + hij via MFMA -> sf, hi, hj
    sm_mfma_kernel<<<(NB * NP + 31) / 32, 256, 0, stream>>>(
        x1, x2, x3, smw1t, smw2t, ecw1t, ws + OFF_SMB1, ws + OFF_SMB2, sf, hi, hj);

    // 7) global max pool + hg projection
    gmax1_kernel<<<NB * 25, 128, 0, stream>>>(sf, gp);
    gfin_kernel<<<NB, 128, 0, stream>>>(gp, ws + OFF_ECW1, ws + OFF_ECB1, hgb);

    // 8) pairwise scorer (32x32 tiles, float4 o-loop)
    dim3 pgrid(32, 32, NB);
    pair_kernel<<<pgrid, 256, 0, stream>>>(hi, hj, hgb, ws + OFF_ECW2, ws + OFF_ECB2,
                                           d_out, flag);
}

// Round 16
// 310.320 us; speedup vs baseline: 1.2762x; 1.2762x over previous
//
#include <hip/hip_runtime.h>
#include <hip/hip_bf16.h>
#include <cmath>

// Problem constants (B=2, N=1000, k=8 from reference)
#define NB 2
#define NP 1000
#define KNN 8
#define PPAIR 499500  // N*(N-1)/2
#define JSPLIT 8

typedef __hip_bfloat16 bf16;
typedef unsigned long long u64;
typedef unsigned short ushort;
typedef unsigned int uint;
typedef __attribute__((ext_vector_type(8))) short short8;
typedef __attribute__((ext_vector_type(4))) float f32x4;

__device__ __forceinline__ float b2f(bf16 v) { return __bfloat162float(v); }
// f32 -> bf16 bits, round-to-nearest-even
__device__ __forceinline__ ushort f2b(float f) {
    uint x = __float_as_uint(f);
    return (ushort)((x + 0x7FFFu + ((x >> 16) & 1u)) >> 16);
}
// flag-aware element load from an input buffer
__device__ __forceinline__ float ldin(const void* p, int flag, int i) {
    return flag ? ((const float*)p)[i] : b2f(((const bf16*)p)[i]);
}

// Workspace layout (float offsets), all 16B-aligned
#define OFF_POS    0
#define OFF_C1W1   6000
#define OFF_C1B1   6096
#define OFF_C1W2   6112
#define OFF_C1B2   6624
#define OFF_C2W1   6656
#define OFF_C2B1   10752
#define OFF_C2W2   10816
#define OFF_C2B2   19008
#define OFF_C3W1   19136
#define OFF_C3B1   84672
#define OFF_C3W2   84928
#define OFF_C3B2   216000
#define OFF_SMW1   216512
#define OFF_SMB1   388544
#define OFF_SMW2   388800
#define OFF_SMB2   421568
#define OFF_ECW1   421696
#define OFF_ECB1   470848
#define OFF_ECW2   470976
#define OFF_ECB2   471104
#define OFF_X1     471112
#define OFF_X2     535112
#define OFF_X3     791112
#define OFF_SF     1815112
#define OFF_G      2071112
#define OFF_HI     2071368
#define OFF_HJ     2327368
#define OFF_HG     2583368
#define OFF_FLAG   2583624   // int
#define OFF_NIDX   2583632   // 16000 ints
#define OFF_GP     2599632   // 50*128 partial max
#define OFF_W1T    2606032   // ec3 W1T 256x256 bf16 (32768 f32)
#define OFF_W2T    2638800   // ec3 W2T 512x256 bf16 (65536 f32)
#define OFF_SMW1T  2704336   // sm W1T 256x672 bf16 (86016 f32)
#define OFF_SMW2T  2790352   // sm W2T 128x256 bf16 (16384 f32)
#define OFF_ECW1T  2806736   // hij WT 256x128 bf16 (16384 f32)
#define OFF_PL     2823120   // JSPLIT*NB*NP*8 u64 partials (256000 f32)
#define OFF_E2W1T  3079120   // ec2 W1T 64x64 bf16 (2048 f32)
#define OFF_E2W2T  3081168   // ec2 W2T 128x64 bf16 (4096 f32)

// ---------------- dtype detection ----------------
__global__ void detect_kernel(const void* pos, int* flag) {
    __shared__ float red[256];
    const unsigned short* p = (const unsigned short*)pos;
    float m = 0.f;
    for (int t = threadIdx.x; t < 6000; t += 256) {
        unsigned int u = ((unsigned int)p[t]) << 16;
        float v = fabsf(__uint_as_float(u));
        if (!isfinite(v)) v = 1e30f;
        m = fmaxf(m, v);
    }
    red[threadIdx.x] = m;
    __syncthreads();
    for (int s = 128; s > 0; s >>= 1) {
        if (threadIdx.x < s) red[threadIdx.x] = fmaxf(red[threadIdx.x], red[threadIdx.x + s]);
        __syncthreads();
    }
    if (threadIdx.x == 0) flag[0] = (red[0] > 1e6f) ? 1 : 0;
}

// ---------------- convert inputs to f32 + build transposed bf16 weights ----------------
struct InPtrs { const void* p[21]; };

__global__ void cvt_all_kernel(InPtrs in, float* ws, const int* flag,
                               ushort* w1t, ushort* w2t, ushort* smw1t,
                               ushort* smw2t, ushort* ecw1t,
                               ushort* e2w1t, ushort* e2w2t) {
    const int sizes[21] = {6000, 96, 16, 512, 32, 4096, 64, 8192, 128,
                           65536, 256, 131072, 512, 172032, 256, 32768, 128,
                           49152, 128, 128, 1};
    const int offs[21] = {OFF_POS, OFF_C1W1, OFF_C1B1, OFF_C1W2, OFF_C1B2,
                          OFF_C2W1, OFF_C2B1, OFF_C2W2, OFF_C2B2,
                          OFF_C3W1, OFF_C3B1, OFF_C3W2, OFF_C3B2,
                          OFF_SMW1, OFF_SMB1, OFF_SMW2, OFF_SMB2,
                          OFF_ECW1, OFF_ECB1, OFF_ECW2, OFF_ECB2};
    int y = blockIdx.y;
    int t = blockIdx.x * 256 + threadIdx.x;
    int f = flag[0];
    if (y < 21) {
        if (t < sizes[y]) ws[offs[y] + t] = ldin(in.p[y], f, t);
    } else if (y == 21) {
        if (t < 65536) {            // ec3 W1 [c=256][h=256] -> [h][c]
            int h = t >> 8, c = t & 255;
            w1t[t] = f2b(ldin(in.p[9], f, c * 256 + h));
        }
    } else if (y == 22) {
        if (t < 131072) {           // ec3 W2 [h=256][o=512] -> [o][h]
            int o = t >> 8, h = t & 255;
            w2t[t] = f2b(ldin(in.p[11], f, h * 512 + o));
        }
    } else if (y == 23) {
        if (t < 172032) {           // sm W1 [c=672][h=256] -> [h][c]
            int h = t / 672, c = t - h * 672;
            smw1t[t] = f2b(ldin(in.p[13], f, c * 256 + h));
        }
    } else if (y == 24) {
        if (t < 32768) {            // sm W2 [h=256][o=128] -> [o][h]
            int o = t >> 8, h = t & 255;
            smw2t[t] = f2b(ldin(in.p[15], f, h * 128 + o));
        }
    } else if (y == 25) {
        if (t < 32768) {            // ec W1[:256] -> [o'][c]
            int op = t >> 7, c = t & 127;
            int idx = (op < 128) ? (c * 128 + op) : ((128 + c) * 128 + (op - 128));
            ecw1t[t] = f2b(ldin(in.p[17], f, idx));
        }
    } else if (y == 26) {
        if (t < 4096) {             // ec2 W1 [c=64][h=64] -> [h][c]
            int h = t >> 6, c = t & 63;
            e2w1t[t] = f2b(ldin(in.p[5], f, c * 64 + h));
        }
    } else {
        if (t < 8192) {             // ec2 W2 [h=64][o=128] -> [o][h]
            int o = t >> 6, h = t & 63;
            e2w2t[t] = f2b(ldin(in.p[7], f, h * 128 + o));
        }
    }
}

// ---------------- shared kNN helpers ----------------
__device__ __forceinline__ void ce(u64& a, u64& b) {
    u64 lo = a < b ? a : b;
    u64 hi = a < b ? b : a;
    a = lo; b = hi;
}

__device__ __forceinline__ void ins8(u64 (&best)[KNN], u64 cand) {
    u64 cur = cand;
    #pragma unroll
    for (int r = 0; r < KNN; ++r) {
        u64 lo = best[r] < cur ? best[r] : cur;
        u64 hi = best[r] < cur ? cur : best[r];
        best[r] = lo; cur = hi;
    }
}

// ---------------- kNN fused (R7-proven): wave per query, for small C ----------------
template <int C>
__global__ __launch_bounds__(256) void knn_fused_kernel(const float* __restrict__ x,
                                                        int* __restrict__ nidx) {
    constexpr int CP = (C + 3) & ~3;
    constexpr int PSTR = CP + 4;
    __shared__ float Qs[8 * PSTR];
    __shared__ float Ps[64 * PSTR];
    int tid = threadIdx.x;
    int b = blockIdx.y;
    int i0 = blockIdx.x * 8;
    int q = tid >> 5;
    int jcol = tid & 31;

    for (int idx = tid; idx < 8 * CP; idx += 256) {
        int row = idx / CP, c = idx % CP;
        int i = i0 + row;
        Qs[row * PSTR + c] = (c < C && i < NP) ? x[((size_t)b * NP + i) * C + c] : 0.f;
    }

    u64 best[KNN];
    #pragma unroll
    for (int r = 0; r < KNN; ++r) best[r] = ~0ull;

    for (int jc = 0; jc < 16; ++jc) {
        int j0 = jc * 64;
        __syncthreads();
        if (C % 4 == 0) {
            for (int idx = tid; idx < 64 * (C / 4); idx += 256) {
                int row = idx / (C / 4), c4 = idx % (C / 4);
                int j = j0 + row;
                float4 v = make_float4(0.f, 0.f, 0.f, 0.f);
                if (j < NP) v = *(const float4*)(x + ((size_t)b * NP + j) * C + c4 * 4);
                *(float4*)(&Ps[row * PSTR + c4 * 4]) = v;
            }
        } else {
            for (int idx = tid; idx < 64 * CP; idx += 256) {
                int row = idx / CP, c = idx % CP;
                int j = j0 + row;
                Ps[row * PSTR + c] = (c < C && j < NP) ? x[((size_t)b * NP + j) * C + c] : 0.f;
            }
        }
        __syncthreads();
        float d0 = 0.f, d1 = 0.f;
        #pragma unroll
        for (int c4 = 0; c4 < CP / 4; ++c4) {
            float4 qv = *(const float4*)(&Qs[q * PSTR + c4 * 4]);
            float4 p0 = *(const float4*)(&Ps[jcol * PSTR + c4 * 4]);
            float4 p1 = *(const float4*)(&Ps[(jcol + 32) * PSTR + c4 * 4]);
            float t;
            t = qv.x - p0.x; d0 += t * t;  t = qv.y - p0.y; d0 += t * t;
            t = qv.z - p0.z; d0 += t * t;  t = qv.w - p0.w; d0 += t * t;
            t = qv.x - p1.x; d1 += t * t;  t = qv.y - p1.y; d1 += t * t;
            t = qv.z - p1.z; d1 += t * t;  t = qv.w - p1.w; d1 += t * t;
        }
        int ja = j0 + jcol, jb = j0 + jcol + 32;
        u64 ca = (ja < NP) ? ((((u64)__float_as_uint(d0)) << 32) | (unsigned)ja) : ~0ull;
        u64 cb = (jb < NP) ? ((((u64)__float_as_uint(d1)) << 32) | (unsigned)jb) : ~0ull;
        ins8(best, ca);
        ins8(best, cb);
    }

    #pragma unroll
    for (int m = 1; m < 32; m <<= 1) {
        u64 other[KNN];
        #pragma unroll
        for (int r = 0; r < KNN; ++r)
            other[r] = __shfl_xor((unsigned long long)best[r], m, 64);
        u64 v[KNN];
        #pragma unroll
        for (int r = 0; r < KNN; ++r)
            v[r] = best[r] < other[7 - r] ? best[r] : other[7 - r];
        ce(v[0], v[4]); ce(v[1], v[5]); ce(v[2], v[6]); ce(v[3], v[7]);
        ce(v[0], v[2]); ce(v[1], v[3]); ce(v[4], v[6]); ce(v[5], v[7]);
        ce(v[0], v[1]); ce(v[2], v[3]); ce(v[4], v[5]); ce(v[6], v[7]);
        #pragma unroll
        for (int r = 0; r < KNN; ++r) best[r] = v[r];
    }

    int i = i0 + q;
    if (jcol == 0 && i < NP) {
        #pragma unroll
        for (int r = 0; r < KNN; ++r)
            nidx[((size_t)b * NP + i) * KNN + r] = (int)(best[r] & 0xffffffffu);
    }
}

// ---------------- kNN v5 (C=128 ONLY): register-tiled, unroll-capped ----------------
// NOTE (R15 lesson): this structure has a ~45 us fixed per-launch cost
// (top-8 insert + u64 butterfly); only profitable at C=128.
template <int C>
__global__ __launch_bounds__(256) void knn5_kernel(const float* __restrict__ x,
                                                   u64* __restrict__ pl) {
    constexpr int CP = (C + 3) & ~3;
    constexpr int STR = CP + 4;
    __shared__ float As[32 * STR];
    __shared__ float Bs[64 * STR];
    int tid = threadIdx.x;
    int tx = tid & 31, ty = tid >> 5;
    int b = blockIdx.z;
    int i0 = blockIdx.x * 32;
    int jbase = blockIdx.y * 128;

    for (int idx = tid; idx < 32 * (CP / 4); idx += 256) {
        int row = idx / (CP / 4), c4 = idx % (CP / 4);
        int i = i0 + row;
        float4 v = make_float4(0.f, 0.f, 0.f, 0.f);
        if (i < NP) v = *(const float4*)(x + ((size_t)b * NP + i) * C + c4 * 4);
        *(float4*)(&As[row * STR + c4 * 4]) = v;
    }

    u64 best[4][KNN];
    #pragma unroll
    for (int r = 0; r < 4; ++r)
        #pragma unroll
        for (int s = 0; s < KNN; ++s) best[r][s] = ~0ull;

    for (int jc = 0; jc < 2; ++jc) {
        int j0 = jbase + jc * 64;
        __syncthreads();
        for (int idx = tid; idx < 64 * (CP / 4); idx += 256) {
            int row = idx / (CP / 4), c4 = idx % (CP / 4);
            int j = j0 + row;
            float4 v = make_float4(0.f, 0.f, 0.f, 0.f);
            if (j < NP) v = *(const float4*)(x + ((size_t)b * NP + j) * C + c4 * 4);
            *(float4*)(&Bs[row * STR + c4 * 4]) = v;
        }
        __syncthreads();

        float acc[4][2];
        #pragma unroll
        for (int r = 0; r < 4; ++r) { acc[r][0] = 0.f; acc[r][1] = 0.f; }
        #pragma unroll 4
        for (int k4 = 0; k4 < CP / 4; ++k4) {
            float4 b0 = *(const float4*)(&Bs[tx * STR + k4 * 4]);
            float4 b1 = *(const float4*)(&Bs[(tx + 32) * STR + k4 * 4]);
            #pragma unroll
            for (int r = 0; r < 4; ++r) {
                float4 a = *(const float4*)(&As[(ty * 4 + r) * STR + k4 * 4]);
                float d;
                d = a.x - b0.x; acc[r][0] += d * d;  d = a.x - b1.x; acc[r][1] += d * d;
                d = a.y - b0.y; acc[r][0] += d * d;  d = a.y - b1.y; acc[r][1] += d * d;
                d = a.z - b0.z; acc[r][0] += d * d;  d = a.z - b1.z; acc[r][1] += d * d;
                d = a.w - b0.w; acc[r][0] += d * d;  d = a.w - b1.w; acc[r][1] += d * d;
            }
        }
        int ja = j0 + tx, jb = j0 + tx + 32;
        #pragma unroll
        for (int r = 0; r < 4; ++r) {
            u64 ca = (ja < NP) ? ((((u64)__float_as_uint(acc[r][0])) << 32) | (unsigned)ja) : ~0ull;
            u64 cb = (jb < NP) ? ((((u64)__float_as_uint(acc[r][1])) << 32) | (unsigned)jb) : ~0ull;
            ins8(best[r], ca);
            ins8(best[r], cb);
        }
    }

    #pragma unroll
    for (int m = 1; m < 32; m <<= 1) {
        #pragma unroll
        for (int r = 0; r < 4; ++r) {
            u64 other[KNN];
            #pragma unroll
            for (int s = 0; s < KNN; ++s)
                other[s] = __shfl_xor((unsigned long long)best[r][s], m, 64);
            u64 v[KNN];
            #pragma unroll
            for (int s = 0; s < KNN; ++s)
                v[s] = best[r][s] < other[7 - s] ? best[r][s] : other[7 - s];
            ce(v[0], v[4]); ce(v[1], v[5]); ce(v[2], v[6]); ce(v[3], v[7]);
            ce(v[0], v[2]); ce(v[1], v[3]); ce(v[4], v[6]); ce(v[5], v[7]);
            ce(v[0], v[1]); ce(v[2], v[3]); ce(v[4], v[5]); ce(v[6], v[7]);
            #pragma unroll
            for (int s = 0; s < KNN; ++s) best[r][s] = v[s];
        }
    }

    if (tx == 0) {
        #pragma unroll
        for (int r = 0; r < 4; ++r) {
            int i = i0 + ty * 4 + r;
            if (i < NP) {
                size_t base = ((size_t)blockIdx.y * NB * NP + (size_t)b * NP + i) * KNN;
                #pragma unroll
                for (int s = 0; s < KNN; ++s) pl[base + s] = best[r][s];
            }
        }
    }
}

// merge JSPLIT partial lists per query -> final top-8 indices
__global__ void knn_merge_kernel(const u64* __restrict__ pl, int* __restrict__ nidx) {
    int t = blockIdx.x * 256 + threadIdx.x;
    if (t >= NB * NP) return;
    u64 best[KNN];
    #pragma unroll
    for (int s = 0; s < KNN; ++s) best[s] = ~0ull;
    for (int js = 0; js < JSPLIT; ++js) {
        #pragma unroll
        for (int s = 0; s < KNN; ++s)
            ins8(best, pl[((size_t)js * NB * NP + t) * KNN + s]);
    }
    #pragma unroll
    for (int s = 0; s < KNN; ++s)
        nidx[(size_t)t * KNN + s] = (int)(best[s] & 0xffffffffu);
}

// ---------------- fused EdgeConv (f32, layer 1 only) ----------------
template <int CIN, int CHID, int COUT>
__global__ void edgeconv_kernel(const float* __restrict__ x, const int* __restrict__ nidx,
                                const float* __restrict__ w1, const float* __restrict__ b1,
                                const float* __restrict__ w2, const float* __restrict__ b2,
                                float* __restrict__ y) {
    int bi = blockIdx.x;
    int b = bi / NP;
    __shared__ float xi[CIN];
    __shared__ float dx[KNN][CIN];
    __shared__ __align__(16) float hid[CHID][12];
    __shared__ int nb[KNN];
    int tid = threadIdx.x;
    if (tid < KNN) nb[tid] = nidx[bi * KNN + tid];
    for (int c = tid; c < CIN; c += 256) xi[c] = x[(size_t)bi * CIN + c];
    __syncthreads();
    for (int t = tid; t < KNN * CIN; t += 256) {
        int k = t / CIN, c = t % CIN;
        dx[k][c] = x[((size_t)b * NP + nb[k]) * CIN + c] - xi[c];
    }
    __syncthreads();
    for (int h = tid; h < CHID; h += 256) {
        float common = b1[h];
        for (int c = 0; c < CIN; ++c) common += xi[c] * w1[c * CHID + h];
        float acc[KNN];
        for (int k = 0; k < KNN; ++k) acc[k] = common;
        for (int c = 0; c < CIN; ++c) {
            float wv = w1[(CIN + c) * CHID + h];
            for (int k = 0; k < KNN; ++k) acc[k] += dx[k][c] * wv;
        }
        for (int k = 0; k < KNN; ++k) hid[h][k] = fmaxf(acc[k], 0.f);
    }
    __syncthreads();
    for (int o = tid; o < COUT; o += 256) {
        float acc[KNN];
        for (int k = 0; k < KNN; ++k) acc[k] = 0.f;
        for (int h = 0; h < CHID; ++h) {
            float wv = w2[h * COUT + o];
            float4 h0 = *(const float4*)&hid[h][0];
            float4 h1 = *(const float4*)&hid[h][4];
            acc[0] += h0.x * wv; acc[1] += h0.y * wv; acc[2] += h0.z * wv; acc[3] += h0.w * wv;
            acc[4] += h1.x * wv; acc[5] += h1.y * wv; acc[6] += h1.z * wv; acc[7] += h1.w * wv;
        }
        float m = acc[0];
        for (int k = 1; k < KNN; ++k) m = fmaxf(m, acc[k]);
        y[(size_t)bi * COUT + o] = m + b2[o];
    }
}

// ---------------- EdgeConv-2 via bf16 MFMA (ec3 template, K=64) ----------------
#define E2STR 72
__global__ __launch_bounds__(256) void ec2_mfma_kernel(
        const float* __restrict__ x1, const int* __restrict__ nidx,
        const ushort* __restrict__ w1t, const ushort* __restrict__ w2t,
        const float* __restrict__ b1f, const float* __restrict__ b2f,
        float* __restrict__ x2out) {
    __shared__ ushort Elds[32 * E2STR];
    __shared__ ushort Hlds[32 * E2STR];
    int tid = threadIdx.x;
    int P0 = blockIdx.x * 4;

    {
        int e = tid >> 3, seg = tid & 7;
        int bi = P0 + (e >> 3), k = e & 7;
        int b = bi / NP;
        int nb = nidx[bi * KNN + k];
        const float* xi = x1 + (size_t)bi * 32;
        const float* xj = x1 + ((size_t)b * NP + nb) * 32;
        int c0 = seg * 8;
        #pragma unroll
        for (int c = c0; c < c0 + 8; c += 4) {
            float4 v;
            if (c < 32) {
                v = *(const float4*)(xi + c);
            } else {
                float4 a = *(const float4*)(xi + c - 32);
                float4 q = *(const float4*)(xj + c - 32);
                v = make_float4(q.x - a.x, q.y - a.y, q.z - a.z, q.w - a.w);
            }
            uint lo = (uint)f2b(v.x) | ((uint)f2b(v.y) << 16);
            uint hi = (uint)f2b(v.z) | ((uint)f2b(v.w) << 16);
            *(uint2*)(&Elds[e * E2STR + c]) = make_uint2(lo, hi);
        }
    }
    __syncthreads();

    int lane = tid & 63, wave = tid >> 6;
    int n16 = lane & 15, quad = lane >> 4;

    {
        int nc = wave * 16;
        f32x4 acc[2];
        float bv = b1f[nc + n16];
        acc[0] = (f32x4){bv, bv, bv, bv};
        acc[1] = acc[0];
        #pragma unroll
        for (int k8 = 0; k8 < 2; ++k8) {
            int ko = k8 * 32 + quad * 8;
            short8 a0 = *(const short8*)(&Elds[(n16) * E2STR + ko]);
            short8 a1 = *(const short8*)(&Elds[(16 + n16) * E2STR + ko]);
            short8 bfr = *(const short8*)(&w1t[(size_t)(nc + n16) * 64 + ko]);
            acc[0] = __builtin_amdgcn_mfma_f32_16x16x32_bf16(a0, bfr, acc[0], 0, 0, 0);
            acc[1] = __builtin_amdgcn_mfma_f32_16x16x32_bf16(a1, bfr, acc[1], 0, 0, 0);
        }
        #pragma unroll
        for (int mt = 0; mt < 2; ++mt) {
            int col = nc + n16;
            #pragma unroll
            for (int r = 0; r < 4; ++r) {
                int row = mt * 16 + quad * 4 + r;
                Hlds[row * E2STR + col] = f2b(fmaxf(acc[mt][r], 0.f));
            }
        }
    }
    __syncthreads();

    {
        int nc2 = wave * 32;
        f32x4 acc[2][2];
        #pragma unroll
        for (int mt = 0; mt < 2; ++mt)
            #pragma unroll
            for (int nt = 0; nt < 2; ++nt) acc[mt][nt] = (f32x4){0.f, 0.f, 0.f, 0.f};
        #pragma unroll
        for (int k8 = 0; k8 < 2; ++k8) {
            int ko = k8 * 32 + quad * 8;
            short8 a0 = *(const short8*)(&Hlds[(n16) * E2STR + ko]);
            short8 a1 = *(const short8*)(&Hlds[(16 + n16) * E2STR + ko]);
            #pragma unroll
            for (int nt = 0; nt < 2; ++nt) {
                short8 bfr = *(const short8*)(&w2t[(size_t)(nc2 + nt * 16 + n16) * 64 + ko]);
                acc[0][nt] = __builtin_amdgcn_mfma_f32_16x16x32_bf16(a0, bfr, acc[0][nt], 0, 0, 0);
                acc[1][nt] = __builtin_amdgcn_mfma_f32_16x16x32_bf16(a1, bfr, acc[1][nt], 0, 0, 0);
            }
        }
        #pragma unroll
        for (int mt = 0; mt < 2; ++mt)
            #pragma unroll
            for (int nt = 0; nt < 2; ++nt) {
                f32x4 a = acc[mt][nt];
                float v = fmaxf(fmaxf(a[0], a[1]), fmaxf(a[2], a[3]));
                float o = fmaxf(v, __shfl_xor(v, 16, 64));
                int col = nc2 + nt * 16 + n16;
                if (quad == 0)
                    x2out[(size_t)(P0 + mt * 2) * 128 + col] = o + b2f[col];
                else if (quad == 2)
                    x2out[(size_t)(P0 + mt * 2 + 1) * 128 + col] = o + b2f[col];
            }
    }
}

// ---------------- EdgeConv-3 via bf16 MFMA, fully fused ----------------
#define ESTR 264   // LDS row stride (bf16 elems)
__global__ __launch_bounds__(256) void ec3_mfma_kernel(
        const float* __restrict__ x2, const int* __restrict__ nidx,
        const ushort* __restrict__ w1t, const ushort* __restrict__ w2t,
        const float* __restrict__ b1f, const float* __restrict__ b2f,
        float* __restrict__ x3) {
    __shared__ ushort Elds[32 * ESTR];
    __shared__ ushort Hlds[32 * ESTR];
    int tid = threadIdx.x;
    int P0 = blockIdx.x * 4;

    {
        int e = tid >> 3, seg = tid & 7;
        int bi = P0 + (e >> 3), k = e & 7;
        int b = bi / NP;
        int nb = nidx[bi * KNN + k];
        const float* xi = x2 + (size_t)bi * 128;
        const float* xj = x2 + ((size_t)b * NP + nb) * 128;
        int c0 = seg * 16;
        #pragma unroll
        for (int c = c0; c < c0 + 16; c += 4) {
            float4 a = *(const float4*)(xi + c);
            float4 q = *(const float4*)(xj + c);
            uint lo = (uint)f2b(a.x) | ((uint)f2b(a.y) << 16);
            uint hi = (uint)f2b(a.z) | ((uint)f2b(a.w) << 16);
            *(uint2*)(&Elds[e * ESTR + c]) = make_uint2(lo, hi);
            lo = (uint)f2b(q.x - a.x) | ((uint)f2b(q.y - a.y) << 16);
            hi = (uint)f2b(q.z - a.z) | ((uint)f2b(q.w - a.w) << 16);
            *(uint2*)(&Elds[e * ESTR + 128 + c]) = make_uint2(lo, hi);
        }
    }
    __syncthreads();

    int lane = tid & 63, wave = tid >> 6;
    int n16 = lane & 15, quad = lane >> 4;

    {
        int nc = wave * 64;
        f32x4 acc1[2][4];
        #pragma unroll
        for (int mt = 0; mt < 2; ++mt)
            #pragma unroll
            for (int nt = 0; nt < 4; ++nt) {
                float bv = b1f[nc + nt * 16 + n16];
                acc1[mt][nt] = (f32x4){bv, bv, bv, bv};
            }
        #pragma unroll
        for (int k8 = 0; k8 < 8; ++k8) {
            int ko = k8 * 32 + quad * 8;
            short8 a0 = *(const short8*)(&Elds[(n16) * ESTR + ko]);
            short8 a1 = *(const short8*)(&Elds[(16 + n16) * ESTR + ko]);
            #pragma unroll
            for (int nt = 0; nt < 4; ++nt) {
                short8 bfr = *(const short8*)(&w1t[(size_t)(nc + nt * 16 + n16) * 256 + ko]);
                acc1[0][nt] = __builtin_amdgcn_mfma_f32_16x16x32_bf16(a0, bfr, acc1[0][nt], 0, 0, 0);
                acc1[1][nt] = __builtin_amdgcn_mfma_f32_16x16x32_bf16(a1, bfr, acc1[1][nt], 0, 0, 0);
            }
        }
        #pragma unroll
        for (int mt = 0; mt < 2; ++mt)
            #pragma unroll
            for (int nt = 0; nt < 4; ++nt) {
                int col = nc + nt * 16 + n16;
                #pragma unroll
                for (int r = 0; r < 4; ++r) {
                    int row = mt * 16 + quad * 4 + r;
                    Hlds[row * ESTR + col] = f2b(fmaxf(acc1[mt][nt][r], 0.f));
                }
            }
    }
    __syncthreads();

    {
        int nc2 = wave * 128;
        f32x4 acc2[2][8];
        #pragma unroll
        for (int mt = 0; mt < 2; ++mt)
            #pragma unroll
            for (int nt = 0; nt < 8; ++nt) acc2[mt][nt] = (f32x4){0.f, 0.f, 0.f, 0.f};
        #pragma unroll
        for (int k8 = 0; k8 < 8; ++k8) {
            int ko = k8 * 32 + quad * 8;
            short8 a0 = *(const short8*)(&Hlds[(n16) * ESTR + ko]);
            short8 a1 = *(const short8*)(&Hlds[(16 + n16) * ESTR + ko]);
            #pragma unroll
            for (int nt = 0; nt < 8; ++nt) {
                short8 bfr = *(const short8*)(&w2t[(size_t)(nc2 + nt * 16 + n16) * 256 + ko]);
                acc2[0][nt] = __builtin_amdgcn_mfma_f32_16x16x32_bf16(a0, bfr, acc2[0][nt], 0, 0, 0);
                acc2[1][nt] = __builtin_amdgcn_mfma_f32_16x16x32_bf16(a1, bfr, acc2[1][nt], 0, 0, 0);
            }
        }
        #pragma unroll
        for (int mt = 0; mt < 2; ++mt)
            #pragma unroll
            for (int nt = 0; nt < 8; ++nt) {
                f32x4 a = acc2[mt][nt];
                float v = fmaxf(fmaxf(a[0], a[1]), fmaxf(a[2], a[3]));
                float o = fmaxf(v, __shfl_xor(v, 16, 64));
                int col = nc2 + nt * 16 + n16;
                if (quad == 0)
                    x3[(size_t)(P0 + mt * 2) * 512 + col] = o + b2f[col];
                else if (quad == 2)
                    x3[(size_t)(P0 + mt * 2 + 1) * 512 + col] = o + b2f[col];
            }
    }
}

// ---------------- shared MLP + hij via bf16 MFMA, fully fused ----------------
#define XSTR 680   // 672+8 bf16
#define SSTR 136   // 128+8
__global__ __launch_bounds__(256) void sm_mfma_kernel(
        const float* __restrict__ x1, const float* __restrict__ x2,
        const float* __restrict__ x3,
        const ushort* __restrict__ w1t, const ushort* __restrict__ w2t,
        const ushort* __restrict__ ecw1t,
        const float* __restrict__ b1f, const float* __restrict__ b2f,
        float* __restrict__ sf, float* __restrict__ hi, float* __restrict__ hj) {
    __shared__ ushort Xlds[32 * XSTR];
    __shared__ ushort Hlds[32 * ESTR];
    __shared__ ushort Slds[32 * SSTR];
    int tid = threadIdx.x;
    int P0 = blockIdx.x * 32;

    {
        int row = tid >> 3, cseg = tid & 7;
        int p = P0 + row;
        bool ok = p < NB * NP;
        #pragma unroll
        for (int k = 0; k < 21; ++k) {
            int c = cseg * 4 + k * 32;
            float4 v = make_float4(0.f, 0.f, 0.f, 0.f);
            if (ok) {
                if (c < 32) v = *(const float4*)(x1 + (size_t)p * 32 + c);
                else if (c < 160) v = *(const float4*)(x2 + (size_t)p * 128 + (c - 32));
                else v = *(const float4*)(x3 + (size_t)p * 512 + (c - 160));
            }
            uint lo = (uint)f2b(v.x) | ((uint)f2b(v.y) << 16);
            uint hv = (uint)f2b(v.z) | ((uint)f2b(v.w) << 16);
            *(uint2*)(&Xlds[row * XSTR + c]) = make_uint2(lo, hv);
        }
    }
    __syncthreads();

    int lane = tid & 63, wave = tid >> 6;
    int n16 = lane & 15, quad = lane >> 4;

    {
        int nc = wave * 64;
        f32x4 acc[2][4];
        #pragma unroll
        for (int mt = 0; mt < 2; ++mt)
            #pragma unroll
            for (int nt = 0; nt < 4; ++nt) {
                float bv = b1f[nc + nt * 16 + n16];
                acc[mt][nt] = (f32x4){bv, bv, bv, bv};
            }
        #pragma unroll
        for (int k8 = 0; k8 < 21; ++k8) {
            int ko = k8 * 32 + quad * 8;
            short8 a0 = *(const short8*)(&Xlds[(n16) * XSTR + ko]);
            short8 a1 = *(const short8*)(&Xlds[(16 + n16) * XSTR + ko]);
            #pragma unroll
            for (int nt = 0; nt < 4; ++nt) {
                short8 bfr = *(const short8*)(&w1t[(size_t)(nc + nt * 16 + n16) * 672 + ko]);
                acc[0][nt] = __builtin_amdgcn_mfma_f32_16x16x32_bf16(a0, bfr, acc[0][nt], 0, 0, 0);
                acc[1][nt] = __builtin_amdgcn_mfma_f32_16x16x32_bf16(a1, bfr, acc[1][nt], 0, 0, 0);
            }
        }
        #pragma unroll
        for (int mt = 0; mt < 2; ++mt)
            #pragma unroll
            for (int nt = 0; nt < 4; ++nt) {
                int col = nc + nt * 16 + n16;
                #pragma unroll
                for (int r = 0; r < 4; ++r) {
                    int row = mt * 16 + quad * 4 + r;
                    Hlds[row * ESTR + col] = f2b(fmaxf(acc[mt][nt][r], 0.f));
                }
            }
    }
    __syncthreads();

    {
        int nc = wave * 32;
        f32x4 acc[2][2];
        #pragma unroll
        for (int mt = 0; mt < 2; ++mt)
            #pragma unroll
            for (int nt = 0; nt < 2; ++nt) {
                float bv = b2f[nc + nt * 16 + n16];
                acc[mt][nt] = (f32x4){bv, bv, bv, bv};
            }
        #pragma unroll
        for (int k8 = 0; k8 < 8; ++k8) {
            int ko = k8 * 32 + quad * 8;
            short8 a0 = *(const short8*)(&Hlds[(n16) * ESTR + ko]);
            short8 a1 = *(const short8*)(&Hlds[(16 + n16) * ESTR + ko]);
            #pragma unroll
            for (int nt = 0; nt < 2; ++nt) {
                short8 bfr = *(const short8*)(&w2t[(size_t)(nc + nt * 16 + n16) * 256 + ko]);
                acc[0][nt] = __builtin_amdgcn_mfma_f32_16x16x32_bf16(a0, bfr, acc[0][nt], 0, 0, 0);
                acc[1][nt] = __builtin_amdgcn_mfma_f32_16x16x32_bf16(a1, bfr, acc[1][nt], 0, 0, 0);
            }
        }
        #pragma unroll
        for (int mt = 0; mt < 2; ++mt)
            #pragma unroll
            for (int nt = 0; nt < 2; ++nt) {
                int col = nc + nt * 16 + n16;
                #pragma unroll
                for (int r = 0; r < 4; ++r) {
                    int row = mt * 16 + quad * 4 + r;
                    int p = P0 + row;
                    float v = acc[mt][nt][r];
                    if (p < NB * NP) sf[(size_t)p * 128 + col] = v;
                    Slds[row * SSTR + col] = f2b(v);
                }
            }
    }
    __syncthreads();

    {
        int nc = wave * 64;
        f32x4 acc[2][4];
        #pragma unroll
        for (int mt = 0; mt < 2; ++mt)
            #pragma unroll
            for (int nt = 0; nt < 4; ++nt) acc[mt][nt] = (f32x4){0.f, 0.f, 0.f, 0.f};
        #pragma unroll
        for (int k8 = 0; k8 < 4; ++k8) {
            int ko = k8 * 32 + quad * 8;
            short8 a0 = *(const short8*)(&Slds[(n16) * SSTR + ko]);
            short8 a1 = *(const short8*)(&Slds[(16 + n16) * SSTR + ko]);
            #pragma unroll
            for (int nt = 0; nt < 4; ++nt) {
                short8 bfr = *(const short8*)(&ecw1t[(size_t)(nc + nt * 16 + n16) * 128 + ko]);
                acc[0][nt] = __builtin_amdgcn_mfma_f32_16x16x32_bf16(a0, bfr, acc[0][nt], 0, 0, 0);
                acc[1][nt] = __builtin_amdgcn_mfma_f32_16x16x32_bf16(a1, bfr, acc[1][nt], 0, 0, 0);
            }
        }
        #pragma unroll
        for (int mt = 0; mt < 2; ++mt)
            #pragma unroll
            for (int nt = 0; nt < 4; ++nt) {
                int colp = nc + nt * 16 + n16;
                float* dst = (colp < 128) ? hi : hj;
                int col = colp & 127;
                #pragma unroll
                for (int r = 0; r < 4; ++r) {
                    int row = mt * 16 + quad * 4 + r;
                    int p = P0 + row;
                    if (p < NB * NP) dst[(size_t)p * 128 + col] = acc[mt][nt][r];
                }
            }
    }
}

// ---------------- global max pool stage 1 ----------------
__global__ void gmax1_kernel(const float* __restrict__ sf, float* __restrict__ part) {
    int m = blockIdx.x;
    int b = m / 25, ch = m % 25, o = threadIdx.x;
    float v = -INFINITY;
    int n0 = ch * 40;
    for (int n = n0; n < n0 + 40; ++n)
        v = fmaxf(v, sf[((size_t)b * NP + n) * 128 + o]);
    part[(size_t)m * 128 + o] = v;
}

// ---------------- fused final max + hg = g @ W[256:384] + b1 ----------------
__global__ void gfin_kernel(const float* __restrict__ part, const float* __restrict__ w1,
                            const float* __restrict__ b1, float* __restrict__ hg) {
    int b = blockIdx.x, o = threadIdx.x;   // 128 threads
    __shared__ float gs[128];
    float v = -INFINITY;
    for (int ch = 0; ch < 25; ++ch)
        v = fmaxf(v, part[((size_t)b * 25 + ch) * 128 + o]);
    gs[o] = v;
    __syncthreads();
    float acc = b1[o];
    for (int c = 0; c < 128; ++c) acc += gs[c] * w1[(256 + c) * 128 + o];
    hg[b * 128 + o] = acc;
}

// ---------------- pairwise scorer: 32x32 tiles, float4 o-loop (R14-proven) ----------------
__global__ __launch_bounds__(256) void pair_kernel(
        const float* __restrict__ hi, const float* __restrict__ hj,
        const float* __restrict__ hg,
        const float* __restrict__ w2, const float* __restrict__ b2,
        void* __restrict__ out, const int* __restrict__ flag) {
    int j0 = blockIdx.x * 32, i0 = blockIdx.y * 32, b = blockIdx.z;
    if (j0 + 31 <= i0) return;
    __shared__ float hit[32][132];
    __shared__ float hjt[32][132];
    __shared__ __align__(16) float w2s[128];
    int tid = threadIdx.x;
    if (tid < 128) w2s[tid] = w2[tid];
    for (int t = tid; t < 32 * 128; t += 256) {
        int r = t >> 7, c = t & 127;
        int i = i0 + r, j = j0 + r;
        hit[r][c] = (i < NP) ? hi[((size_t)b * NP + i) * 128 + c] : 0.f;
        hjt[r][c] = ((j < NP) ? hj[((size_t)b * NP + j) * 128 + c] : 0.f) + hg[b * 128 + c];
    }
    __syncthreads();
    float bb = b2[0];
    int f = flag[0];
    int tj = tid & 31;
    int ti0 = tid >> 5;
    int j = j0 + tj;
    float acc[4] = {0.f, 0.f, 0.f, 0.f};
    #pragma unroll 4
    for (int o4 = 0; o4 < 32; ++o4) {
        float4 hv = *(const float4*)(&hjt[tj][o4 * 4]);
        float4 wv = *(const float4*)(&w2s[o4 * 4]);
        #pragma unroll
        for (int r = 0; r < 4; ++r) {
            float4 a = *(const float4*)(&hit[ti0 + 8 * r][o4 * 4]);
            acc[r] += fmaxf(a.x + hv.x, 0.f) * wv.x
                    + fmaxf(a.y + hv.y, 0.f) * wv.y
                    + fmaxf(a.z + hv.z, 0.f) * wv.z
                    + fmaxf(a.w + hv.w, 0.f) * wv.w;
        }
    }
    #pragma unroll
    for (int r = 0; r < 4; ++r) {
        int i = i0 + ti0 + 8 * r;
        if (i < j && j < NP) {
            size_t p = (size_t)i * (NP - 1) - (size_t)i * (i - 1) / 2 + (j - i - 1);
            float mo = acc[r] + bb;
            float pr = 1.f / (1.f + expf(-mo));
            size_t idx0 = (size_t)b * PPAIR + p;
            size_t idx1 = (size_t)NB * PPAIR + idx0;
            if (f) {
                ((float*)out)[idx0] = pr;
                ((float*)out)[idx1] = mo;
            } else {
                ((bf16*)out)[idx0] = __float2bfloat16(pr);
                ((bf16*)out)[idx1] = __float2bfloat16(mo);
            }
        }
    }
}

extern "C" void kernel_launch(void* const* d_in, const int* in_sizes, int n_in,
                              void* d_out, int out_size, void* d_ws, size_t ws_size,
                              hipStream_t stream) {
    float* ws = (float*)d_ws;
    float* posf = ws + OFF_POS;
    float* x1   = ws + OFF_X1;
    float* x2   = ws + OFF_X2;
    float* x3   = ws + OFF_X3;
    float* sf   = ws + OFF_SF;
    float* hi   = ws + OFF_HI;
    float* hj   = ws + OFF_HJ;
    float* hgb  = ws + OFF_HG;
    int*   flag = (int*)(ws + OFF_FLAG);
    int*   nidx = (int*)(ws + OFF_NIDX);
    float* gp   = ws + OFF_GP;
    ushort* w1t = (ushort*)(ws + OFF_W1T);
    ushort* w2t = (ushort*)(ws + OFF_W2T);
    ushort* smw1t = (ushort*)(ws + OFF_SMW1T);
    ushort* smw2t = (ushort*)(ws + OFF_SMW2T);
    ushort* ecw1t = (ushort*)(ws + OFF_ECW1T);
    ushort* e2w1t = (ushort*)(ws + OFF_E2W1T);
    ushort* e2w2t = (ushort*)(ws + OFF_E2W2T);
    u64*    pl  = (u64*)(ws + OFF_PL);

    // 1) detect input dtype (bf16 vs f32) on-device
    detect_kernel<<<1, 256, 0, stream>>>(d_in[0], flag);

    // 2) convert all inputs to f32 + build all transposed bf16 weights (one kernel)
    InPtrs ip;
    for (int i = 0; i < 21; ++i) ip.p[i] = d_in[i];
    dim3 cgrid(672, 28);
    cvt_all_kernel<<<cgrid, 256, 0, stream>>>(ip, ws, flag, w1t, w2t, smw1t, smw2t,
                                              ecw1t, e2w1t, e2w2t);

    dim3 kgrid_f(NP / 8, NB);                      // knn_fused (small C)
    dim3 kgrid5((NP + 31) / 32, JSPLIT, NB);       // knn5 (C=128), 128-j splits

    // 3) EdgeConv 1 (C=3 -> 32)
    knn_fused_kernel<3><<<kgrid_f, 256, 0, stream>>>(posf, nidx);
    edgeconv_kernel<3, 16, 32><<<NB * NP, 256, 0, stream>>>(
        posf, nidx, ws + OFF_C1W1, ws + OFF_C1B1, ws + OFF_C1W2, ws + OFF_C1B2, x1);

    // 4) EdgeConv 2 (C=32 -> 128) via MFMA
    knn_fused_kernel<32><<<kgrid_f, 256, 0, stream>>>(x1, nidx);
    ec2_mfma_kernel<<<NB * NP / 4, 256, 0, stream>>>(
        x1, nidx, e2w1t, e2w2t, ws + OFF_C2B1, ws + OFF_C2B2, x2);

    // 5) EdgeConv 3 (C=128 -> 512) via MFMA
    knn5_kernel<128><<<kgrid5, 256, 0, stream>>>(x2, pl);
    knn_merge_kernel<<<(NB * NP + 255) / 256, 256, 0, stream>>>(pl, nidx);
    ec3_mfma_kernel<<<NB * NP / 4, 256, 0, stream>>>(
        x2, nidx, w1t, w2t, ws + OFF_C3B1, ws + OFF_C3B2, x3);

    // 6) shared MLP + hij via MFMA -> sf, hi, hj
    sm_mfma_kernel<<<(NB * NP + 31) / 32, 256, 0, stream>>>(
        x1, x2, x3, smw1t, smw2t, ecw1t, ws + OFF_SMB1, ws + OFF_SMB2, sf, hi, hj);

    // 7) global max pool + hg projection
    gmax1_kernel<<<NB * 25, 128, 0, stream>>>(sf, gp);
    gfin_kernel<<<NB, 128, 0, stream>>>(gp, ws + OFF_ECW1, ws + OFF_ECB1, hgb);

    // 8) pairwise scorer (32x32 tiles, float4 o-loop)
    dim3 pgrid(32, 32, NB);
    pair_kernel<<<pgrid, 256, 0, stream>>>(hi, hj, hgb, ws + OFF_ECW2, ws + OFF_ECB2,
                                           d_out, flag);
}